// Round 1
// baseline (413.785 us; speedup 1.0000x reference)
//
#include <hip/hip_runtime.h>
#include <math.h>

#define TPB 256

// ---------- complex helpers ----------
__device__ __forceinline__ float2 cmul(float2 a, float2 b) {
    return make_float2(a.x * b.x - a.y * b.y, a.x * b.y + a.y * b.x);
}
__device__ __forceinline__ float2 cmulc(float2 a, float2 b) {  // conj(a)*b
    return make_float2(a.x * b.x + a.y * b.y, a.x * b.y - a.y * b.x);
}
__device__ __forceinline__ float2 cdivf(float2 a, float2 b) {
    float inv = 1.0f / (b.x * b.x + b.y * b.y);
    return make_float2((a.x * b.x + a.y * b.y) * inv, (a.y * b.x - a.x * b.y) * inv);
}
__device__ __forceinline__ int brev12(int x) { return (int)(__brev((unsigned)x) >> 20); }
__device__ __forceinline__ int brev11(int x) { return (int)(__brev((unsigned)x) >> 21); }

// ---------- in-LDS FFT cores (256 threads) ----------
// DIF: natural-order input, bit-reversed output. dir = -1 fwd, +1 inv (unnormalized).
template <int LOGN>
__device__ void fft_dif(float2* s, int tid, float dir) {
    const int N = 1 << LOGN;
    for (int st = LOGN - 1; st >= 0; --st) {
        __syncthreads();
        int half = 1 << st;
        for (int b = tid; b < (N >> 1); b += TPB) {
            int j  = b & (half - 1);
            int i0 = ((b >> st) << (st + 1)) + j;
            int i1 = i0 + half;
            float2 u = s[i0], v = s[i1];
            float ang = dir * 3.14159265358979f * (float)j / (float)half;
            float c, sn;
            __sincosf(ang, &sn, &c);
            float2 d = make_float2(u.x - v.x, u.y - v.y);
            s[i0] = make_float2(u.x + v.x, u.y + v.y);
            s[i1] = cmul(make_float2(c, sn), d);
        }
    }
    __syncthreads();
}

// DIT: bit-reversed input, natural-order output. dir = -1 fwd, +1 inv (unnormalized).
template <int LOGN>
__device__ void fft_dit(float2* s, int tid, float dir) {
    const int N = 1 << LOGN;
    for (int st = 0; st < LOGN; ++st) {
        __syncthreads();
        int half = 1 << st;
        for (int b = tid; b < (N >> 1); b += TPB) {
            int j  = b & (half - 1);
            int i0 = ((b >> st) << (st + 1)) + j;
            int i1 = i0 + half;
            float ang = dir * 3.14159265358979f * (float)j / (float)half;
            float c, sn;
            __sincosf(ang, &sn, &c);
            float2 t = cmul(make_float2(c, sn), s[i1]);
            float2 u = s[i0];
            s[i0] = make_float2(u.x + t.x, u.y + t.y);
            s[i1] = make_float2(u.x - t.x, u.y - t.y);
        }
    }
    __syncthreads();
}

// ---------- kernel A: k_f[h, f] via Cauchy + Woodbury ----------
// grid (512, 4); block 256. kf layout: [H, 2049] float2.
__global__ __launch_bounds__(TPB) void kf_kernel(
    const float* __restrict__ log_dt, const float* __restrict__ w_ri,
    const float* __restrict__ Bri, const float* __restrict__ Cri,
    float2* __restrict__ kf) {
    __shared__ float2 vs[4][32];  // v[a*2+b][n] = conj(C[h,a,n]) * B[h,b,n]
    __shared__ float2 wds[32];
    const int h   = blockIdx.x;
    const int tid = threadIdx.x;
    const float dt = expf(log_dt[h]);
    if (tid < 32) {
        float wr = w_ri[2 * tid], wi = w_ri[2 * tid + 1];
        wds[tid] = make_float2(wr * dt, wi * dt);
    }
    if (tid < 128) {
        int a = tid >> 6, b = (tid >> 5) & 1, n = tid & 31;
        const float* Cp = Cri + (((h * 2 + a) * 32) + n) * 2;
        const float* Bp = Bri + (((h * 2 + b) * 32) + n) * 2;
        float Cr = Cp[0], Ci = Cp[1], Br = Bp[0], Bi = Bp[1];
        vs[a * 2 + b][n] = make_float2(Cr * Br + Ci * Bi, Cr * Bi - Ci * Br);
    }
    __syncthreads();
    const int by   = blockIdx.y;
    const int fend = (by == 3) ? 2049 : (by + 1) * 512;
    for (int f = by * 512 + tid; f < fend; f += TPB) {
        // freq = exp(-i*2*pi*f/4096); precise trig (Nyquist denominator is ~1e-7)
        float th = (6.283185307179586f / 4096.0f) * (float)f;
        float cf = cosf(th), sf = sinf(th);
        float2 freq = make_float2(cf, -sf);
        float2 den  = make_float2(1.0f + freq.x, freq.y);       // 1 + freq
        float2 z    = cdivf(make_float2(2.0f * (1.0f - freq.x), -2.0f * freq.y), den);
        float2 r00 = make_float2(0.f, 0.f), r01 = r00, r10 = r00, r11 = r00;
        for (int n = 0; n < 32; ++n) {
            float2 wd = wds[n];
            float2 d1 = make_float2(z.x - wd.x, z.y - wd.y);
            float i1  = 1.0f / (d1.x * d1.x + d1.y * d1.y);
            float2 K1 = make_float2(d1.x * i1, -d1.y * i1);     // 1/(z - wd)
            float2 d2 = make_float2(z.x - wd.x, z.y + wd.y);
            float i2  = 1.0f / (d2.x * d2.x + d2.y * d2.y);
            float2 K2 = make_float2(d2.x * i2, -d2.y * i2);     // 1/(z - conj(wd))
            float2 v, t;
            v = vs[0][n]; t = cmul(v, K1); r00.x += t.x; r00.y += t.y;
                          t = cmulc(v, K2); r00.x += t.x; r00.y += t.y;
            v = vs[1][n]; t = cmul(v, K1); r01.x += t.x; r01.y += t.y;
                          t = cmulc(v, K2); r01.x += t.x; r01.y += t.y;
            v = vs[2][n]; t = cmul(v, K1); r10.x += t.x; r10.y += t.y;
                          t = cmulc(v, K2); r10.x += t.x; r10.y += t.y;
            v = vs[3][n]; t = cmul(v, K1); r11.x += t.x; r11.y += t.y;
                          t = cmulc(v, K2); r11.x += t.x; r11.y += t.y;
        }
        r00.x *= dt; r00.y *= dt; r01.x *= dt; r01.y *= dt;
        r10.x *= dt; r10.y *= dt; r11.x *= dt; r11.y *= dt;
        float2 q  = cdivf(cmul(r01, r10), make_float2(1.0f + r11.x, r11.y));
        float2 k0 = make_float2(r00.x - q.x, r00.y - q.y);
        float2 kv = cmul(k0, cdivf(make_float2(2.0f, 0.0f), den));
        kf[h * 2049 + f] = kv;
    }
}

// ---------- kernel B: k[h,:] = irfft_4096(k_f[h,:]) ----------
__global__ __launch_bounds__(TPB) void irfftk_kernel(const float2* __restrict__ kf,
                                                     float* __restrict__ kt) {
    __shared__ float2 s[2048];
    const int h = blockIdx.x, tid = threadIdx.x;
    const float2* X = kf + h * 2049;
    for (int m = tid; m < 2048; m += TPB) {
        float2 Xm = X[m];
        float2 Xc = X[2048 - m];
        if (m == 0) { Xm.y = 0.0f; Xc.y = 0.0f; }  // DC/Nyquist treated real
        float2 A  = make_float2(Xm.x + Xc.x, Xm.y - Xc.y);   // X[m] + conj(X[2048-m])
        float2 Bv = make_float2(Xm.x - Xc.x, Xm.y + Xc.y);   // X[m] - conj(X[2048-m])
        float ang = (3.14159265358979f / 2048.0f) * (float)m;  // +2*pi*m/4096
        float c, sn;
        __sincosf(ang, &sn, &c);
        float2 O = cmul(make_float2(c, sn), Bv);
        s[m] = make_float2(0.5f * (A.x - O.y), 0.5f * (A.y + O.x));  // Y = E + iO
    }
    fft_dif<11>(s, tid, +1.0f);  // inverse, natural-in -> bitrev-out
    float2* ko = (float2*)(kt + (size_t)h * 4096);
    const float sc = 1.0f / 2048.0f;
    for (int t = tid; t < 2048; t += TPB) {
        float2 y = s[brev11(t)];
        ko[t] = make_float2(y.x * sc, y.y * sc);  // k[2t], k[2t+1]
    }
}

// ---------- kernel C: K~ = rfft_8192(k zero-padded), stored in BIT-REVERSED slot order ----------
// Kt layout: [H, 4097]; Kt[h][p] = Kf8192[brev12(p)] for p<4096, Kt[h][4096] = Kf8192[4096].
__global__ __launch_bounds__(TPB) void rfftk_kernel(const float* __restrict__ kt,
                                                    float2* __restrict__ Kt) {
    __shared__ float2 s[4096];
    const int h = blockIdx.x, tid = threadIdx.x;
    const float2* xr = (const float2*)(kt + (size_t)h * 4096);
    for (int t = tid; t < 4096; t += TPB)
        s[t] = (t < 2048) ? xr[t] : make_float2(0.f, 0.f);
    fft_dif<12>(s, tid, -1.0f);  // slot p holds Y[brev12(p)]
    float2* K = Kt + (size_t)h * 4097;
    for (int p = tid; p < 4096; p += TPB) {
        int j  = brev12(p);
        int jc = (4096 - j) & 4095;
        int pc = brev12(jc);
        float2 Yj = s[p], Yc = s[pc];
        float2 A  = make_float2(Yj.x + Yc.x, Yj.y - Yc.y);
        float2 Bv = make_float2(Yj.x - Yc.x, Yj.y + Yc.y);
        float ang = -(3.14159265358979f / 4096.0f) * (float)j;  // -2*pi*j/8192
        float c, sn;
        __sincosf(ang, &sn, &c);
        float2 t2 = cmul(make_float2(c, sn), make_float2(Bv.y, -Bv.x));  // W * (-i*Bv)
        K[p] = make_float2(0.5f * (A.x + t2.x), 0.5f * (A.y + t2.y));
        if (p == 0) K[4096] = make_float2(Yj.x - Yj.y, 0.0f);
    }
}

// ---------- transpose in: x[b,t,h] -> xt[(b*512+h), t] ----------
__global__ __launch_bounds__(TPB) void transpose_in(const float* __restrict__ x,
                                                    float* __restrict__ xt) {
    __shared__ float tile[64][65];
    const int b = blockIdx.z, t0 = blockIdx.y * 64, h0 = blockIdx.x * 64;
    const int tx = threadIdx.x & 63, ty = threadIdx.x >> 6;
    const float* xp = x + ((size_t)b * 4096 + t0) * 512 + h0;
    for (int i = 0; i < 16; ++i) {
        int tl = ty + 4 * i;
        tile[tl][tx] = xp[(size_t)tl * 512 + tx];
    }
    __syncthreads();
    float* xo = xt + ((size_t)(b * 512 + h0)) * 4096 + t0;
    for (int i = 0; i < 16; ++i) {
        int hl = ty + 4 * i;
        xo[(size_t)hl * 4096 + tx] = tile[tx][hl];
    }
}

// ---------- fused conv: y_row = irfft8192( rfft8192(x_row) * K~ ) , first 4096 samples ----------
// xt and yt may alias (row fully read into LDS before stores) -> no __restrict__ on them.
__global__ __launch_bounds__(TPB) void conv_kernel(const float* xt,
                                                   const float2* __restrict__ Kt,
                                                   float* yt) {
    __shared__ float2 s[4096];
    const int row = blockIdx.x, tid = threadIdx.x;
    const int h = row & 511;
    const float2* xr = (const float2*)(xt + (size_t)row * 4096);
    for (int t = tid; t < 4096; t += TPB)
        s[t] = (t < 2048) ? xr[t] : make_float2(0.f, 0.f);
    fft_dif<12>(s, tid, -1.0f);  // bitrev-domain spectrum of packed row
    const float2* K = Kt + (size_t)h * 4097;
    for (int p = tid; p < 4096; p += TPB) {
        if (p == 0) {  // j=0 pairs with bin 4096
            float2 Y0 = s[0];
            float X0 = Y0.x + Y0.y;
            float Xn = Y0.x - Y0.y;
            float Z0 = X0 * K[0].x;
            float Zn = Xn * K[4096].x;
            s[0] = make_float2(0.5f * (Z0 + Zn), 0.5f * (Z0 - Zn));
            continue;
        }
        int j  = brev12(p);
        int jc = 4096 - j;
        int pc = brev12(jc);
        if (pc < p) continue;  // partner thread handles the pair
        float2 Yj = s[p], Yc = s[pc];
        float2 A  = make_float2(Yj.x + Yc.x, Yj.y - Yc.y);   // Yj + conj(Yc)
        float2 Bv = make_float2(Yj.x - Yc.x, Yj.y + Yc.y);   // Yj - conj(Yc)
        float ang = -(3.14159265358979f / 4096.0f) * (float)j;  // W = e^{-2pi i j/8192}
        float c, sn;
        __sincosf(ang, &sn, &c);
        float2 W = make_float2(c, sn);
        // X[j] = (A + W*(-i*Bv))/2
        float2 t2 = cmul(W, make_float2(Bv.y, -Bv.x));
        float2 Xj = make_float2(0.5f * (A.x + t2.x), 0.5f * (A.y + t2.y));
        // X[jc] = (conj(A) + (-conj(W))*(-i*{-Bv.x,Bv.y}))/2
        float2 t2c = cmul(make_float2(-W.x, W.y), make_float2(Bv.y, Bv.x));
        float2 Xc2 = make_float2(0.5f * (A.x + t2c.x), 0.5f * (-A.y + t2c.y));
        // pointwise multiply with kernel spectrum (bit-rev stored)
        float2 Zj = cmul(Xj, K[p]);
        float2 Zc = cmul(Xc2, K[pc]);
        // repack for inverse: Y'[j] = E' + iO', E' = (Zj + conj(Zc))/2, O' = conj(W)*(Zj - conj(Zc))/2
        float2 A2 = make_float2(Zj.x + Zc.x, Zj.y - Zc.y);
        float2 B2 = make_float2(Zj.x - Zc.x, Zj.y + Zc.y);
        float2 O2 = cmul(make_float2(W.x, -W.y), B2);
        s[p] = make_float2(0.5f * (A2.x - O2.y), 0.5f * (A2.y + O2.x));
        if (pc != p) {
            // Y'[jc]: A2c = conj(A2); B2c = {-B2.x, B2.y}; W^{+jc} = {-W.x, -W.y}
            float2 O2c = cmul(make_float2(-W.x, -W.y), make_float2(-B2.x, B2.y));
            s[pc] = make_float2(0.5f * (A2.x - O2c.y), 0.5f * (-A2.y + O2c.x));
        }
    }
    fft_dit<12>(s, tid, +1.0f);  // inverse, bitrev-in -> natural-out
    float2* yo = (float2*)(yt + (size_t)row * 4096);
    const float sc = 1.0f / 4096.0f;
    for (int t = tid; t < 2048; t += TPB) {  // keep first 4096 real samples only
        float2 y = s[t];
        yo[t] = make_float2(y.x * sc, y.y * sc);
    }
}

// ---------- transpose out + skip: out[b,t,h] = yt[(b*512+h),t] + D[h]*x[b,t,h] ----------
__global__ __launch_bounds__(TPB) void transpose_out(const float* __restrict__ yt,
                                                     const float* __restrict__ x,
                                                     const float* __restrict__ Dv,
                                                     float* __restrict__ out) {
    __shared__ float tile[64][65];
    const int b = blockIdx.z, t0 = blockIdx.y * 64, h0 = blockIdx.x * 64;
    const int tx = threadIdx.x & 63, ty = threadIdx.x >> 6;
    const float* yp = yt + ((size_t)(b * 512 + h0)) * 4096 + t0;
    for (int i = 0; i < 16; ++i) {
        int hl = ty + 4 * i;
        tile[hl][tx] = yp[(size_t)hl * 4096 + tx];
    }
    __syncthreads();
    const float d   = Dv[h0 + tx];
    const float* xp = x + ((size_t)b * 4096 + t0) * 512 + h0;
    float* op       = out + ((size_t)b * 4096 + t0) * 512 + h0;
    for (int i = 0; i < 16; ++i) {
        int tl = ty + 4 * i;
        op[(size_t)tl * 512 + tx] = tile[tx][tl] + d * xp[(size_t)tl * 512 + tx];
    }
}

extern "C" void kernel_launch(void* const* d_in, const int* in_sizes, int n_in,
                              void* d_out, int out_size, void* d_ws, size_t ws_size,
                              hipStream_t stream) {
    (void)in_sizes; (void)n_in; (void)out_size; (void)ws_size;
    const float* x      = (const float*)d_in[0];  // [8,4096,512]
    const float* log_dt = (const float*)d_in[1];  // [512]
    const float* w_ri   = (const float*)d_in[2];  // [32,2]
    const float* Bri    = (const float*)d_in[3];  // [512,2,32,2]
    const float* Cri    = (const float*)d_in[4];  // [512,2,32,2]
    const float* Dv     = (const float*)d_in[5];  // [512]
    float* out = (float*)d_out;

    char* ws = (char*)d_ws;
    float*  xt = (float*)(ws);                  // 8*512*4096*4 = 67,108,864 B (reused as yt)
    float2* kf = (float2*)(ws + 67108864);      // 512*2049*8   =  8,392,704 B
    float*  kt = (float*)(ws + 75501568);       // 512*4096*4   =  8,388,608 B
    float2* Kt = (float2*)(ws + 83890176);      // 512*4097*8   = 16,781,312 B  (end ~100.7 MB)

    kf_kernel<<<dim3(512, 4), TPB, 0, stream>>>(log_dt, w_ri, Bri, Cri, kf);
    irfftk_kernel<<<512, TPB, 0, stream>>>(kf, kt);
    rfftk_kernel<<<512, TPB, 0, stream>>>(kt, Kt);
    transpose_in<<<dim3(8, 64, 8), TPB, 0, stream>>>(x, xt);
    conv_kernel<<<4096, TPB, 0, stream>>>(xt, Kt, xt);  // y overwrites xt rows
    transpose_out<<<dim3(8, 64, 8), TPB, 0, stream>>>(xt, x, Dv, out);
}

// Round 2
// 365.982 us; speedup vs baseline: 1.1306x; 1.1306x over previous
//
#include <hip/hip_runtime.h>
#include <math.h>

#define TPB 256

// ---------- complex helpers ----------
__device__ __forceinline__ float2 cmul(float2 a, float2 b) {
    return make_float2(a.x * b.x - a.y * b.y, a.x * b.y + a.y * b.x);
}
__device__ __forceinline__ float2 cmulc(float2 a, float2 b) {  // conj(a)*b
    return make_float2(a.x * b.x + a.y * b.y, a.x * b.y - a.y * b.x);
}
__device__ __forceinline__ float2 cdivf(float2 a, float2 b) {
    float inv = 1.0f / (b.x * b.x + b.y * b.y);
    return make_float2((a.x * b.x + a.y * b.y) * inv, (a.y * b.x - a.x * b.y) * inv);
}
__device__ __forceinline__ float2 cadd(float2 a, float2 b) { return make_float2(a.x + b.x, a.y + b.y); }
__device__ __forceinline__ float2 csub(float2 a, float2 b) { return make_float2(a.x - b.x, a.y - b.y); }
__device__ __forceinline__ float2 mul_i(float2 a, float d) {  // a * (i*d)
    return make_float2(-d * a.y, d * a.x);
}
__device__ __forceinline__ int brev11(int x) { return (int)(__brev((unsigned)x) >> 21); }
// base-8 digit reversal of a 12-bit index (4 digits)
__device__ __forceinline__ int rev8(int x) {
    return ((x & 7) << 9) | (((x >> 3) & 7) << 6) | (((x >> 6) & 7) << 3) | ((x >> 9) & 7);
}
// LDS bank swizzle: bijective, spreads every radix-8 stride class across banks
__device__ __forceinline__ int swz(int i) { return i ^ ((i >> 4) & 15) ^ ((i >> 8) & 15); }

// ---------- 8-point DFT core, natural order: y_m = sum_k x_k e^{d*2pi*i*k*m/8} ----------
__device__ __forceinline__ void dft8(const float2* x, float2* y, float d) {
    const float r = 0.70710678118f;
    float2 s0 = cadd(x[0], x[4]), t0 = csub(x[0], x[4]);
    float2 s1 = cadd(x[1], x[5]), t1 = csub(x[1], x[5]);
    float2 s2 = cadd(x[2], x[6]), t2 = csub(x[2], x[6]);
    float2 s3 = cadd(x[3], x[7]), t3 = csub(x[3], x[7]);
    t1 = cmul(t1, make_float2(r, d * r));   // W8^1
    t2 = mul_i(t2, d);                      // W8^2
    t3 = cmul(t3, make_float2(-r, d * r));  // W8^3
    float2 u0 = cadd(s0, s2), v0 = csub(s0, s2);
    float2 u1 = cadd(s1, s3), v1 = mul_i(csub(s1, s3), d);
    y[0] = cadd(u0, u1); y[4] = csub(u0, u1);
    y[2] = cadd(v0, v1); y[6] = csub(v0, v1);
    float2 p0 = cadd(t0, t2), q0 = csub(t0, t2);
    float2 p1 = cadd(t1, t3), q1 = mul_i(csub(t1, t3), d);
    y[1] = cadd(p0, p1); y[5] = csub(p0, p1);
    y[3] = cadd(q0, q1); y[7] = csub(q0, q1);
}

// ---------- radix-8 DIF: natural in -> base-8 digit-reversed out (swizzled LDS) ----------
template <int LOGN>  // LOGN multiple of 3
__device__ void fft8_dif(float2* s, int tid, float dir) {
    const int N = 1 << LOGN;
    for (int hb = LOGN - 3; hb >= 0; hb -= 3) {
        const int h = 1 << hb;
        const float astep = dir * 6.283185307179586f / (float)(h << 3);
        __syncthreads();
        for (int b = tid; b < (N >> 3); b += TPB) {
            int j = b & (h - 1);
            int base = ((b >> hb) << (hb + 3)) + j;
            float2 x[8];
#pragma unroll
            for (int k = 0; k < 8; ++k) x[k] = s[swz(base + k * h)];
            float2 y[8];
            dft8(x, y, dir);
            float ang = astep * (float)j;
            float c, sn;
            __sincosf(ang, &sn, &c);
            float2 w = make_float2(c, sn), wm = w;
            s[swz(base)] = y[0];
#pragma unroll
            for (int m = 1; m < 8; ++m) {
                s[swz(base + m * h)] = cmul(wm, y[m]);
                wm = cmul(wm, w);
            }
        }
    }
    __syncthreads();
}

// ---------- radix-8 DIT: base-8 digit-reversed in -> natural out (swizzled LDS) ----------
template <int LOGN>
__device__ void fft8_dit(float2* s, int tid, float dir) {
    const int N = 1 << LOGN;
    for (int hb = 0; hb < LOGN; hb += 3) {
        const int h = 1 << hb;
        const float astep = dir * 6.283185307179586f / (float)(h << 3);
        __syncthreads();
        for (int b = tid; b < (N >> 3); b += TPB) {
            int j = b & (h - 1);
            int base = ((b >> hb) << (hb + 3)) + j;
            float ang = astep * (float)j;
            float c, sn;
            __sincosf(ang, &sn, &c);
            float2 w = make_float2(c, sn);
            float2 x[8];
            x[0] = s[swz(base)];
            float2 wm = w;
#pragma unroll
            for (int k = 1; k < 8; ++k) {
                x[k] = cmul(wm, s[swz(base + k * h)]);
                wm = cmul(wm, w);
            }
            float2 y[8];
            dft8(x, y, dir);
#pragma unroll
            for (int m = 0; m < 8; ++m) s[swz(base + m * h)] = y[m];
        }
    }
    __syncthreads();
}

// ---------- radix-2 DIF (unswizzled), for the 2048-pt kernel inverse only ----------
template <int LOGN>
__device__ void fft_dif2(float2* s, int tid, float dir) {
    const int N = 1 << LOGN;
    for (int st = LOGN - 1; st >= 0; --st) {
        __syncthreads();
        int half = 1 << st;
        for (int b = tid; b < (N >> 1); b += TPB) {
            int j  = b & (half - 1);
            int i0 = ((b >> st) << (st + 1)) + j;
            int i1 = i0 + half;
            float2 u = s[i0], v = s[i1];
            float ang = dir * 3.14159265358979f * (float)j / (float)half;
            float c, sn;
            __sincosf(ang, &sn, &c);
            float2 d = make_float2(u.x - v.x, u.y - v.y);
            s[i0] = make_float2(u.x + v.x, u.y + v.y);
            s[i1] = cmul(make_float2(c, sn), d);
        }
    }
    __syncthreads();
}

// ---------- kernel A: k_f[h, f] via Cauchy + Woodbury (unchanged, verified) ----------
__global__ __launch_bounds__(TPB) void kf_kernel(
    const float* __restrict__ log_dt, const float* __restrict__ w_ri,
    const float* __restrict__ Bri, const float* __restrict__ Cri,
    float2* __restrict__ kf) {
    __shared__ float2 vs[4][32];
    __shared__ float2 wds[32];
    const int h   = blockIdx.x;
    const int tid = threadIdx.x;
    const float dt = expf(log_dt[h]);
    if (tid < 32) {
        float wr = w_ri[2 * tid], wi = w_ri[2 * tid + 1];
        wds[tid] = make_float2(wr * dt, wi * dt);
    }
    if (tid < 128) {
        int a = tid >> 6, b = (tid >> 5) & 1, n = tid & 31;
        const float* Cp = Cri + (((h * 2 + a) * 32) + n) * 2;
        const float* Bp = Bri + (((h * 2 + b) * 32) + n) * 2;
        float Cr = Cp[0], Ci = Cp[1], Br = Bp[0], Bi = Bp[1];
        vs[a * 2 + b][n] = make_float2(Cr * Br + Ci * Bi, Cr * Bi - Ci * Br);
    }
    __syncthreads();
    const int by   = blockIdx.y;
    const int fend = (by == 3) ? 2049 : (by + 1) * 512;
    for (int f = by * 512 + tid; f < fend; f += TPB) {
        float th = (6.283185307179586f / 4096.0f) * (float)f;
        float cf = cosf(th), sf = sinf(th);
        float2 freq = make_float2(cf, -sf);
        float2 den  = make_float2(1.0f + freq.x, freq.y);
        float2 z    = cdivf(make_float2(2.0f * (1.0f - freq.x), -2.0f * freq.y), den);
        float2 r00 = make_float2(0.f, 0.f), r01 = r00, r10 = r00, r11 = r00;
        for (int n = 0; n < 32; ++n) {
            float2 wd = wds[n];
            float2 d1 = make_float2(z.x - wd.x, z.y - wd.y);
            float i1  = 1.0f / (d1.x * d1.x + d1.y * d1.y);
            float2 K1 = make_float2(d1.x * i1, -d1.y * i1);
            float2 d2 = make_float2(z.x - wd.x, z.y + wd.y);
            float i2  = 1.0f / (d2.x * d2.x + d2.y * d2.y);
            float2 K2 = make_float2(d2.x * i2, -d2.y * i2);
            float2 v, t;
            v = vs[0][n]; t = cmul(v, K1); r00.x += t.x; r00.y += t.y;
                          t = cmulc(v, K2); r00.x += t.x; r00.y += t.y;
            v = vs[1][n]; t = cmul(v, K1); r01.x += t.x; r01.y += t.y;
                          t = cmulc(v, K2); r01.x += t.x; r01.y += t.y;
            v = vs[2][n]; t = cmul(v, K1); r10.x += t.x; r10.y += t.y;
                          t = cmulc(v, K2); r10.x += t.x; r10.y += t.y;
            v = vs[3][n]; t = cmul(v, K1); r11.x += t.x; r11.y += t.y;
                          t = cmulc(v, K2); r11.x += t.x; r11.y += t.y;
        }
        r00.x *= dt; r00.y *= dt; r01.x *= dt; r01.y *= dt;
        r10.x *= dt; r10.y *= dt; r11.x *= dt; r11.y *= dt;
        float2 q  = cdivf(cmul(r01, r10), make_float2(1.0f + r11.x, r11.y));
        float2 k0 = make_float2(r00.x - q.x, r00.y - q.y);
        float2 kv = cmul(k0, cdivf(make_float2(2.0f, 0.0f), den));
        kf[h * 2049 + f] = kv;
    }
}

// ---------- kernel B (fused): irfft_4096(k_f) -> zero-pad -> rfft_8192, store digit-rev ----------
// Kt layout: [H, 4097]; Kt[h][p] = Kf8192[rev8(p)] for p<4096, Kt[h][4096] = Kf8192[4096].
__global__ __launch_bounds__(TPB) void kprep_kernel(const float2* __restrict__ kf,
                                                    float2* __restrict__ Kt) {
    __shared__ float2 s[4096];
    const int hh = blockIdx.x, tid = threadIdx.x;
    const float2* X = kf + hh * 2049;
    // pack 2049-bin Hermitian spectrum into 2048-pt complex inverse-FFT input
    for (int m = tid; m < 2048; m += TPB) {
        float2 Xm = X[m];
        float2 Xc = X[2048 - m];
        if (m == 0) { Xm.y = 0.0f; Xc.y = 0.0f; }
        float2 A  = make_float2(Xm.x + Xc.x, Xm.y - Xc.y);
        float2 Bv = make_float2(Xm.x - Xc.x, Xm.y + Xc.y);
        float ang = (3.14159265358979f / 2048.0f) * (float)m;
        float c, sn;
        __sincosf(ang, &sn, &c);
        float2 O = cmul(make_float2(c, sn), Bv);
        s[m] = make_float2(0.5f * (A.x - O.y), 0.5f * (A.y + O.x));
    }
    fft_dif2<11>(s, tid, +1.0f);  // inverse, natural-in -> bitrev-out (unswizzled)
    // gather k (time domain) to registers, then scatter into swizzled zero-padded buffer
    float2 reg[8];
    const float sc = 1.0f / 2048.0f;
#pragma unroll
    for (int i = 0; i < 8; ++i) {
        int t = tid + TPB * i;  // 0..2047
        float2 v = s[brev11(t)];
        reg[i] = make_float2(v.x * sc, v.y * sc);
    }
    __syncthreads();
#pragma unroll
    for (int i = 0; i < 8; ++i) {
        int t = tid + TPB * i;
        s[swz(t)]        = reg[i];
        s[swz(t + 2048)] = make_float2(0.f, 0.f);
    }
    fft8_dif<12>(s, tid, -1.0f);  // slot p holds Y[rev8(p)]
    float2* K = Kt + (size_t)hh * 4097;
    for (int p = tid; p < 4096; p += TPB) {
        int j  = rev8(p);
        int jc = (4096 - j) & 4095;
        int pc = rev8(jc);
        float2 Yj = s[swz(p)], Yc = s[swz(pc)];
        float2 A  = make_float2(Yj.x + Yc.x, Yj.y - Yc.y);
        float2 Bv = make_float2(Yj.x - Yc.x, Yj.y + Yc.y);
        float ang = -(3.14159265358979f / 4096.0f) * (float)j;
        float c, sn;
        __sincosf(ang, &sn, &c);
        float2 t2 = cmul(make_float2(c, sn), make_float2(Bv.y, -Bv.x));
        K[p] = make_float2(0.5f * (A.x + t2.x), 0.5f * (A.y + t2.y));
        if (p == 0) K[4096] = make_float2(Yj.x - Yj.y, 0.0f);
    }
}

// ---------- transpose in: x[b,t,h] -> xt[(b*512+h), t], float4 both sides ----------
__global__ __launch_bounds__(TPB) void transpose_in(const float* __restrict__ x,
                                                    float* __restrict__ xt) {
    __shared__ float tile[64][65];
    const int b = blockIdx.z, t0 = blockIdx.y * 64, h0 = blockIdx.x * 64;
    const int tid = threadIdx.x;
    const float4* xv = (const float4*)(x + ((size_t)b * 4096 + t0) * 512 + h0);
#pragma unroll
    for (int i = 0; i < 4; ++i) {
        int idx = tid + TPB * i;       // 0..1023
        int tl = idx >> 4, hq = idx & 15;
        float4 v = xv[(size_t)tl * 128 + hq];
        tile[tl][hq * 4 + 0] = v.x; tile[tl][hq * 4 + 1] = v.y;
        tile[tl][hq * 4 + 2] = v.z; tile[tl][hq * 4 + 3] = v.w;
    }
    __syncthreads();
    float* xo = xt + ((size_t)(b * 512 + h0)) * 4096 + t0;
#pragma unroll
    for (int i = 0; i < 4; ++i) {
        int idx = tid + TPB * i;
        int hl = idx >> 4, tq = idx & 15;
        float4 v = make_float4(tile[tq * 4 + 0][hl], tile[tq * 4 + 1][hl],
                               tile[tq * 4 + 2][hl], tile[tq * 4 + 3][hl]);
        ((float4*)(xo + (size_t)hl * 4096))[tq] = v;
    }
}

// ---------- fused conv: y_row = irfft8192( rfft8192(x_row) * K~ )[0:4096], radix-8 ----------
__global__ __launch_bounds__(TPB) void conv_kernel(const float* xt,
                                                   const float2* __restrict__ Kt,
                                                   float* yt) {
    __shared__ float2 s[4096];
    const int row = blockIdx.x, tid = threadIdx.x;
    const int h = row & 511;
    const float2* xr = (const float2*)(xt + (size_t)row * 4096);
    for (int t = tid; t < 4096; t += TPB)
        s[swz(t)] = (t < 2048) ? xr[t] : make_float2(0.f, 0.f);
    fft8_dif<12>(s, tid, -1.0f);  // digit-rev-domain spectrum of packed row
    const float2* K = Kt + (size_t)h * 4097;
    for (int p = tid; p < 4096; p += TPB) {
        if (p == 0) {  // j=0 pairs with bin 4096
            float2 Y0 = s[swz(0)];
            float X0 = Y0.x + Y0.y;
            float Xn = Y0.x - Y0.y;
            float Z0 = X0 * K[0].x;
            float Zn = Xn * K[4096].x;
            s[swz(0)] = make_float2(0.5f * (Z0 + Zn), 0.5f * (Z0 - Zn));
            continue;
        }
        int j  = rev8(p);
        int jc = 4096 - j;
        int pc = rev8(jc & 4095);
        if (pc < p) continue;  // pair owner has the smaller slot
        float2 Yj = s[swz(p)], Yc = s[swz(pc)];
        float2 A  = make_float2(Yj.x + Yc.x, Yj.y - Yc.y);   // Yj + conj(Yc)
        float2 Bv = make_float2(Yj.x - Yc.x, Yj.y + Yc.y);   // Yj - conj(Yc)
        float ang = -(3.14159265358979f / 4096.0f) * (float)j;  // W = e^{-2pi i j/8192}
        float c, sn;
        __sincosf(ang, &sn, &c);
        float2 W = make_float2(c, sn);
        float2 t2 = cmul(W, make_float2(Bv.y, -Bv.x));
        float2 Xj = make_float2(0.5f * (A.x + t2.x), 0.5f * (A.y + t2.y));
        float2 t2c = cmul(make_float2(-W.x, W.y), make_float2(Bv.y, Bv.x));
        float2 Xc2 = make_float2(0.5f * (A.x + t2c.x), 0.5f * (-A.y + t2c.y));
        float2 Zj = cmul(Xj, K[p]);
        float2 Zc = cmul(Xc2, K[pc]);
        float2 A2 = make_float2(Zj.x + Zc.x, Zj.y - Zc.y);
        float2 B2 = make_float2(Zj.x - Zc.x, Zj.y + Zc.y);
        float2 O2 = cmul(make_float2(W.x, -W.y), B2);
        s[swz(p)] = make_float2(0.5f * (A2.x - O2.y), 0.5f * (A2.y + O2.x));
        if (pc != p) {
            float2 O2c = cmul(make_float2(-W.x, -W.y), make_float2(-B2.x, B2.y));
            s[swz(pc)] = make_float2(0.5f * (A2.x - O2c.y), 0.5f * (-A2.y + O2c.x));
        }
    }
    fft8_dit<12>(s, tid, +1.0f);  // inverse, digit-rev-in -> natural-out
    float2* yo = (float2*)(yt + (size_t)row * 4096);
    const float sc = 1.0f / 4096.0f;
    for (int t = tid; t < 2048; t += TPB) {
        float2 y = s[swz(t)];
        yo[t] = make_float2(y.x * sc, y.y * sc);
    }
}

// ---------- transpose out + skip: out[b,t,h] = yt[(b*512+h),t] + D[h]*x[b,t,h], float4 ----------
__global__ __launch_bounds__(TPB) void transpose_out(const float* __restrict__ yt,
                                                     const float* __restrict__ x,
                                                     const float* __restrict__ Dv,
                                                     float* __restrict__ out) {
    __shared__ float tile[64][65];
    const int b = blockIdx.z, t0 = blockIdx.y * 64, h0 = blockIdx.x * 64;
    const int tid = threadIdx.x;
    const float* yp = yt + ((size_t)(b * 512 + h0)) * 4096 + t0;
#pragma unroll
    for (int i = 0; i < 4; ++i) {
        int idx = tid + TPB * i;
        int hl = idx >> 4, tq = idx & 15;
        float4 v = ((const float4*)(yp + (size_t)hl * 4096))[tq];
        tile[tq * 4 + 0][hl] = v.x; tile[tq * 4 + 1][hl] = v.y;
        tile[tq * 4 + 2][hl] = v.z; tile[tq * 4 + 3][hl] = v.w;
    }
    __syncthreads();
    const float4* xv = (const float4*)(x + ((size_t)b * 4096 + t0) * 512 + h0);
    float4* ov = (float4*)(out + ((size_t)b * 4096 + t0) * 512 + h0);
    const float4* D4 = (const float4*)(Dv + h0);
#pragma unroll
    for (int i = 0; i < 4; ++i) {
        int idx = tid + TPB * i;
        int tl = idx >> 4, hq = idx & 15;
        float4 xvv = xv[(size_t)tl * 128 + hq];
        float4 d = D4[hq];
        float4 v = make_float4(tile[tl][4 * hq + 0] + d.x * xvv.x,
                               tile[tl][4 * hq + 1] + d.y * xvv.y,
                               tile[tl][4 * hq + 2] + d.z * xvv.z,
                               tile[tl][4 * hq + 3] + d.w * xvv.w);
        ov[(size_t)tl * 128 + hq] = v;
    }
}

extern "C" void kernel_launch(void* const* d_in, const int* in_sizes, int n_in,
                              void* d_out, int out_size, void* d_ws, size_t ws_size,
                              hipStream_t stream) {
    (void)in_sizes; (void)n_in; (void)out_size; (void)ws_size;
    const float* x      = (const float*)d_in[0];  // [8,4096,512]
    const float* log_dt = (const float*)d_in[1];  // [512]
    const float* w_ri   = (const float*)d_in[2];  // [32,2]
    const float* Bri    = (const float*)d_in[3];  // [512,2,32,2]
    const float* Cri    = (const float*)d_in[4];  // [512,2,32,2]
    const float* Dv     = (const float*)d_in[5];  // [512]
    float* out = (float*)d_out;

    char* ws = (char*)d_ws;
    float*  xt = (float*)(ws);                  // 8*512*4096*4 = 67,108,864 B (reused as yt)
    float2* kf = (float2*)(ws + 67108864);      // 512*2049*8   =  8,392,704 B
    float2* Kt = (float2*)(ws + 75501568);      // 512*4097*8   = 16,781,312 B  (end ~92.3 MB)

    kf_kernel<<<dim3(512, 4), TPB, 0, stream>>>(log_dt, w_ri, Bri, Cri, kf);
    kprep_kernel<<<512, TPB, 0, stream>>>(kf, Kt);
    transpose_in<<<dim3(8, 64, 8), TPB, 0, stream>>>(x, xt);
    conv_kernel<<<4096, TPB, 0, stream>>>(xt, Kt, xt);  // y overwrites xt rows
    transpose_out<<<dim3(8, 64, 8), TPB, 0, stream>>>(xt, x, Dv, out);
}

// Round 3
// 303.082 us; speedup vs baseline: 1.3653x; 1.2075x over previous
//
#include <hip/hip_runtime.h>
#include <math.h>

#define TPB 256
#define CTPB 512

// ---------- complex helpers ----------
__device__ __forceinline__ float2 cmul(float2 a, float2 b) {
    return make_float2(a.x * b.x - a.y * b.y, a.x * b.y + a.y * b.x);
}
__device__ __forceinline__ float2 cmulc(float2 a, float2 b) {  // conj(a)*b
    return make_float2(a.x * b.x + a.y * b.y, a.x * b.y - a.y * b.x);
}
__device__ __forceinline__ float2 cdivf(float2 a, float2 b) {
    float inv = 1.0f / (b.x * b.x + b.y * b.y);
    return make_float2((a.x * b.x + a.y * b.y) * inv, (a.y * b.x - a.x * b.y) * inv);
}
__device__ __forceinline__ float2 cadd(float2 a, float2 b) { return make_float2(a.x + b.x, a.y + b.y); }
__device__ __forceinline__ float2 csub(float2 a, float2 b) { return make_float2(a.x - b.x, a.y - b.y); }
__device__ __forceinline__ float2 mul_i(float2 a, float d) {  // a * (i*d)
    return make_float2(-d * a.y, d * a.x);
}
__device__ __forceinline__ int brev11(int x) { return (int)(__brev((unsigned)x) >> 21); }
// base-8 digit reversal of a 12-bit index (4 digits)
__device__ __forceinline__ int rev8(int x) {
    return ((x & 7) << 9) | (((x >> 3) & 7) << 6) | (((x >> 6) & 7) << 3) | ((x >> 9) & 7);
}
// LDS bank swizzle. GF(2)-LINEAR: swz(a^b) == swz(a)^swz(b). This lets us hoist
// one swz per butterfly and fold the per-tap offsets into compile-time XOR constants.
__device__ __forceinline__ int swz(int i) { return i ^ ((i >> 4) & 15) ^ ((i >> 8) & 15); }

// ---------- 8-point DFT core, natural order: y_m = sum_k x_k e^{d*2pi*i*k*m/8} ----------
__device__ __forceinline__ void dft8(const float2* x, float2* y, float d) {
    const float r = 0.70710678118f;
    float2 s0 = cadd(x[0], x[4]), t0 = csub(x[0], x[4]);
    float2 s1 = cadd(x[1], x[5]), t1 = csub(x[1], x[5]);
    float2 s2 = cadd(x[2], x[6]), t2 = csub(x[2], x[6]);
    float2 s3 = cadd(x[3], x[7]), t3 = csub(x[3], x[7]);
    t1 = cmul(t1, make_float2(r, d * r));   // W8^1
    t2 = mul_i(t2, d);                      // W8^2
    t3 = cmul(t3, make_float2(-r, d * r));  // W8^3
    float2 u0 = cadd(s0, s2), v0 = csub(s0, s2);
    float2 u1 = cadd(s1, s3), v1 = mul_i(csub(s1, s3), d);
    y[0] = cadd(u0, u1); y[4] = csub(u0, u1);
    y[2] = cadd(v0, v1); y[6] = csub(v0, v1);
    float2 p0 = cadd(t0, t2), q0 = csub(t0, t2);
    float2 p1 = cadd(t1, t3), q1 = mul_i(csub(t1, t3), d);
    y[1] = cadd(p0, p1); y[5] = csub(p0, p1);
    y[3] = cadd(q0, q1); y[7] = csub(q0, q1);
}

// ---------- radix-8 DIF: natural in -> base-8 digit-reversed out (swizzled LDS) ----------
// base has zero bits at hb..hb+2, so swz(base + k*h) = swz(base) ^ swz(k<<hb) (compile-time).
template <int LOGN, int NT>
__device__ void fft8_dif(float2* s, int tid, float dir) {
    const int N = 1 << LOGN;
#pragma unroll
    for (int hb = LOGN - 3; hb >= 0; hb -= 3) {
        const int h = 1 << hb;
        const float astep = dir * 6.283185307179586f / (float)(h << 3);
        __syncthreads();
#pragma unroll
        for (int it = 0; it < (N >> 3) / NT; ++it) {
            const int b = tid + it * NT;
            int j = b & (h - 1);
            int base = ((b >> hb) << (hb + 3)) + j;
            int s0 = swz(base);
            float2 x[8];
#pragma unroll
            for (int k = 0; k < 8; ++k) x[k] = s[s0 ^ swz(k << hb)];
            float2 y[8];
            dft8(x, y, dir);
            float ang = astep * (float)j;
            float c, sn;
            __sincosf(ang, &sn, &c);
            float2 w = make_float2(c, sn), wm = w;
            s[s0] = y[0];
#pragma unroll
            for (int m = 1; m < 8; ++m) {
                s[s0 ^ swz(m << hb)] = cmul(wm, y[m]);
                wm = cmul(wm, w);
            }
        }
    }
    __syncthreads();
}

// ---------- radix-8 DIT: base-8 digit-reversed in -> natural out (swizzled LDS) ----------
template <int LOGN, int NT>
__device__ void fft8_dit(float2* s, int tid, float dir) {
    const int N = 1 << LOGN;
#pragma unroll
    for (int hb = 0; hb < LOGN; hb += 3) {
        const int h = 1 << hb;
        const float astep = dir * 6.283185307179586f / (float)(h << 3);
        __syncthreads();
#pragma unroll
        for (int it = 0; it < (N >> 3) / NT; ++it) {
            const int b = tid + it * NT;
            int j = b & (h - 1);
            int base = ((b >> hb) << (hb + 3)) + j;
            int s0 = swz(base);
            float ang = astep * (float)j;
            float c, sn;
            __sincosf(ang, &sn, &c);
            float2 w = make_float2(c, sn);
            float2 x[8];
            x[0] = s[s0];
            float2 wm = w;
#pragma unroll
            for (int k = 1; k < 8; ++k) {
                x[k] = cmul(wm, s[s0 ^ swz(k << hb)]);
                wm = cmul(wm, w);
            }
            float2 y[8];
            dft8(x, y, dir);
#pragma unroll
            for (int m = 0; m < 8; ++m) s[s0 ^ swz(m << hb)] = y[m];
        }
    }
    __syncthreads();
}

// ---------- radix-2 DIF (unswizzled), for the 2048-pt kernel inverse only ----------
template <int LOGN>
__device__ void fft_dif2(float2* s, int tid, float dir) {
    const int N = 1 << LOGN;
    for (int st = LOGN - 1; st >= 0; --st) {
        __syncthreads();
        int half = 1 << st;
        for (int b = tid; b < (N >> 1); b += TPB) {
            int j  = b & (half - 1);
            int i0 = ((b >> st) << (st + 1)) + j;
            int i1 = i0 + half;
            float2 u = s[i0], v = s[i1];
            float ang = dir * 3.14159265358979f * (float)j / (float)half;
            float c, sn;
            __sincosf(ang, &sn, &c);
            float2 d = make_float2(u.x - v.x, u.y - v.y);
            s[i0] = make_float2(u.x + v.x, u.y + v.y);
            s[i1] = cmul(make_float2(c, sn), d);
        }
    }
    __syncthreads();
}

// ---------- kernel A: k_f[h, f] via Cauchy + Woodbury, collapsed pair algebra ----------
// z = 2i*tan(theta/2) is purely imaginary, so v/(z-wd) + conj(v)/(z-conj(wd))
//   = (a + i*rho*zeta) / (c + i*d),  a = -2Re(v*conj(wd)), rho = 2Re(v) (per h,n),
//   c = |wd|^2 - zeta^2, d = -2Re(wd)*zeta  (denominator SHARED by all four v_ab).
__global__ __launch_bounds__(TPB) void kf_kernel(
    const float* __restrict__ log_dt, const float* __restrict__ w_ri,
    const float* __restrict__ Bri, const float* __restrict__ Cri,
    float2* __restrict__ kf) {
    __shared__ float2 wds[32];
    __shared__ float aab[4][32], rab[4][32];
    __shared__ float qn[32], pn[32];
    const int h   = blockIdx.x;
    const int tid = threadIdx.x;
    const float dt = expf(log_dt[h]);
    if (tid < 32) {
        float wr = w_ri[2 * tid] * dt, wi = w_ri[2 * tid + 1] * dt;
        wds[tid] = make_float2(wr, wi);
        qn[tid]  = wr * wr + wi * wi;
        pn[tid]  = -2.0f * wr;
    }
    __syncthreads();
    if (tid < 128) {
        int a = tid >> 6, b = (tid >> 5) & 1, n = tid & 31;
        const float* Cp = Cri + (((h * 2 + a) * 32) + n) * 2;
        const float* Bp = Bri + (((h * 2 + b) * 32) + n) * 2;
        float Cr = Cp[0], Ci = Cp[1], Br = Bp[0], Bi = Bp[1];
        float2 v = make_float2(Cr * Br + Ci * Bi, Cr * Bi - Ci * Br);  // conj(C)*B
        float2 wd = wds[n];
        aab[a * 2 + b][n] = -2.0f * (v.x * wd.x + v.y * wd.y);  // -2*Re(v*conj(wd))
        rab[a * 2 + b][n] = 2.0f * v.x;
    }
    __syncthreads();
    const int by   = blockIdx.y;
    const int fend = (by == 3) ? 2049 : (by + 1) * 512;
    for (int f = by * 512 + tid; f < fend; f += TPB) {
        float th = (6.283185307179586f / 4096.0f) * (float)f;
        float cf = cosf(th), sf = sinf(th);
        float2 den = make_float2(1.0f + cf, -sf);      // 1 + freq
        float zt  = 2.0f * tanf(0.5f * th);            // zeta (finite in float for all f)
        float zt2 = zt * zt;
        float2 r00 = make_float2(0.f, 0.f), r01 = r00, r10 = r00, r11 = r00;
        for (int n = 0; n < 32; ++n) {
            float c   = qn[n] - zt2;
            float d   = pn[n] * zt;
            float inv = 1.0f / (c * c + d * d);
            float cc = c * inv, dd = d * inv;
            float a0 = aab[0][n], b0 = rab[0][n] * zt;
            r00.x += a0 * cc + b0 * dd; r00.y += b0 * cc - a0 * dd;
            float a1 = aab[1][n], b1 = rab[1][n] * zt;
            r01.x += a1 * cc + b1 * dd; r01.y += b1 * cc - a1 * dd;
            float a2 = aab[2][n], b2 = rab[2][n] * zt;
            r10.x += a2 * cc + b2 * dd; r10.y += b2 * cc - a2 * dd;
            float a3 = aab[3][n], b3 = rab[3][n] * zt;
            r11.x += a3 * cc + b3 * dd; r11.y += b3 * cc - a3 * dd;
        }
        r00.x *= dt; r00.y *= dt; r01.x *= dt; r01.y *= dt;
        r10.x *= dt; r10.y *= dt; r11.x *= dt; r11.y *= dt;
        float2 q  = cdivf(cmul(r01, r10), make_float2(1.0f + r11.x, r11.y));
        float2 k0 = make_float2(r00.x - q.x, r00.y - q.y);
        float2 kv = cmul(k0, cdivf(make_float2(2.0f, 0.0f), den));
        kf[h * 2049 + f] = kv;
    }
}

// ---------- kernel B (fused): irfft_4096(k_f) -> zero-pad -> rfft_8192, store digit-rev ----------
// Kt layout: [H, 4097]; Kt[h][p] = Kf8192[rev8(p)] for p<4096, Kt[h][4096] = Kf8192[4096].
__global__ __launch_bounds__(TPB) void kprep_kernel(const float2* __restrict__ kf,
                                                    float2* __restrict__ Kt) {
    __shared__ float2 s[4096];
    const int hh = blockIdx.x, tid = threadIdx.x;
    const float2* X = kf + hh * 2049;
    for (int m = tid; m < 2048; m += TPB) {
        float2 Xm = X[m];
        float2 Xc = X[2048 - m];
        if (m == 0) { Xm.y = 0.0f; Xc.y = 0.0f; }
        float2 A  = make_float2(Xm.x + Xc.x, Xm.y - Xc.y);
        float2 Bv = make_float2(Xm.x - Xc.x, Xm.y + Xc.y);
        float ang = (3.14159265358979f / 2048.0f) * (float)m;
        float c, sn;
        __sincosf(ang, &sn, &c);
        float2 O = cmul(make_float2(c, sn), Bv);
        s[m] = make_float2(0.5f * (A.x - O.y), 0.5f * (A.y + O.x));
    }
    fft_dif2<11>(s, tid, +1.0f);  // inverse, natural-in -> bitrev-out (unswizzled)
    float2 reg[8];
    const float sc = 1.0f / 2048.0f;
#pragma unroll
    for (int i = 0; i < 8; ++i) {
        int t = tid + TPB * i;  // 0..2047
        float2 v = s[brev11(t)];
        reg[i] = make_float2(v.x * sc, v.y * sc);
    }
    __syncthreads();
#pragma unroll
    for (int i = 0; i < 8; ++i) {
        int t = tid + TPB * i;
        s[swz(t)]        = reg[i];
        s[swz(t + 2048)] = make_float2(0.f, 0.f);
    }
    fft8_dif<12, TPB>(s, tid, -1.0f);  // slot p holds Y[rev8(p)]
    float2* K = Kt + (size_t)hh * 4097;
    for (int p = tid; p < 4096; p += TPB) {
        int j  = rev8(p);
        int jc = (4096 - j) & 4095;
        int pc = rev8(jc);
        float2 Yj = s[swz(p)], Yc = s[swz(pc)];
        float2 A  = make_float2(Yj.x + Yc.x, Yj.y - Yc.y);
        float2 Bv = make_float2(Yj.x - Yc.x, Yj.y + Yc.y);
        float ang = -(3.14159265358979f / 4096.0f) * (float)j;
        float c, sn;
        __sincosf(ang, &sn, &c);
        float2 t2 = cmul(make_float2(c, sn), make_float2(Bv.y, -Bv.x));
        K[p] = make_float2(0.5f * (A.x + t2.x), 0.5f * (A.y + t2.y));
        if (p == 0) K[4096] = make_float2(Yj.x - Yj.y, 0.0f);
    }
}

// ---------- transpose in: x[b,t,h] -> xt[(b*512+h), t], float4 both sides ----------
__global__ __launch_bounds__(TPB) void transpose_in(const float* __restrict__ x,
                                                    float* __restrict__ xt) {
    __shared__ float tile[64][65];
    const int b = blockIdx.z, t0 = blockIdx.y * 64, h0 = blockIdx.x * 64;
    const int tid = threadIdx.x;
    const float4* xv = (const float4*)(x + ((size_t)b * 4096 + t0) * 512 + h0);
#pragma unroll
    for (int i = 0; i < 4; ++i) {
        int idx = tid + TPB * i;       // 0..1023
        int tl = idx >> 4, hq = idx & 15;
        float4 v = xv[(size_t)tl * 128 + hq];
        tile[tl][hq * 4 + 0] = v.x; tile[tl][hq * 4 + 1] = v.y;
        tile[tl][hq * 4 + 2] = v.z; tile[tl][hq * 4 + 3] = v.w;
    }
    __syncthreads();
    float* xo = xt + ((size_t)(b * 512 + h0)) * 4096 + t0;
#pragma unroll
    for (int i = 0; i < 4; ++i) {
        int idx = tid + TPB * i;
        int hl = idx >> 4, tq = idx & 15;
        float4 v = make_float4(tile[tq * 4 + 0][hl], tile[tq * 4 + 1][hl],
                               tile[tq * 4 + 2][hl], tile[tq * 4 + 3][hl]);
        ((float4*)(xo + (size_t)hl * 4096))[tq] = v;
    }
}

// ---------- fused conv: y_row = irfft8192( rfft8192(x_row) * K~ )[0:4096], radix-8 ----------
__global__ __launch_bounds__(CTPB) void conv_kernel(const float* xt,
                                                    const float2* __restrict__ Kt,
                                                    float* yt) {
    __shared__ float2 s[4096];
    const int row = blockIdx.x, tid = threadIdx.x;
    const int hch = row & 511;
    const int stid = swz(tid);
    const float2* xr = (const float2*)(xt + (size_t)row * 4096);
#pragma unroll
    for (int i = 0; i < 8; ++i) {
        int t = tid + CTPB * i;
        s[stid ^ swz(CTPB * i)] = (t < 2048) ? xr[t] : make_float2(0.f, 0.f);
    }
    fft8_dif<12, CTPB>(s, tid, -1.0f);  // digit-rev-domain spectrum of packed row
    const float2* K = Kt + (size_t)hch * 4097;
#pragma unroll
    for (int i = 0; i < 8; ++i) {
        int p  = tid + CTPB * i;
        int sp = stid ^ swz(CTPB * i);
        if (p == 0) {  // j=0 pairs with bin 4096
            float2 Y0 = s[sp];
            float X0 = Y0.x + Y0.y;
            float Xn = Y0.x - Y0.y;
            float Z0 = X0 * K[0].x;
            float Zn = Xn * K[4096].x;
            s[sp] = make_float2(0.5f * (Z0 + Zn), 0.5f * (Z0 - Zn));
            continue;
        }
        int j  = rev8(p);
        int jc = 4096 - j;
        int pc = rev8(jc & 4095);
        if (pc < p) continue;  // pair owner has the smaller slot
        float2 Yj = s[sp], Yc = s[swz(pc)];
        float2 A  = make_float2(Yj.x + Yc.x, Yj.y - Yc.y);   // Yj + conj(Yc)
        float2 Bv = make_float2(Yj.x - Yc.x, Yj.y + Yc.y);   // Yj - conj(Yc)
        float ang = -(3.14159265358979f / 4096.0f) * (float)j;  // W = e^{-2pi i j/8192}
        float c, sn;
        __sincosf(ang, &sn, &c);
        float2 W = make_float2(c, sn);
        float2 t2 = cmul(W, make_float2(Bv.y, -Bv.x));
        float2 Xj = make_float2(0.5f * (A.x + t2.x), 0.5f * (A.y + t2.y));
        float2 t2c = cmul(make_float2(-W.x, W.y), make_float2(Bv.y, Bv.x));
        float2 Xc2 = make_float2(0.5f * (A.x + t2c.x), 0.5f * (-A.y + t2c.y));
        float2 Zj = cmul(Xj, K[p]);
        float2 Zc = cmul(Xc2, K[pc]);
        float2 A2 = make_float2(Zj.x + Zc.x, Zj.y - Zc.y);
        float2 B2 = make_float2(Zj.x - Zc.x, Zj.y + Zc.y);
        float2 O2 = cmul(make_float2(W.x, -W.y), B2);
        s[sp] = make_float2(0.5f * (A2.x - O2.y), 0.5f * (A2.y + O2.x));
        if (pc != p) {
            float2 O2c = cmul(make_float2(-W.x, -W.y), make_float2(-B2.x, B2.y));
            s[swz(pc)] = make_float2(0.5f * (A2.x - O2c.y), 0.5f * (-A2.y + O2c.x));
        }
    }
    fft8_dit<12, CTPB>(s, tid, +1.0f);  // inverse, digit-rev-in -> natural-out
    float2* yo = (float2*)(yt + (size_t)row * 4096);
    const float sc = 1.0f / 4096.0f;
#pragma unroll
    for (int i = 0; i < 4; ++i) {
        int t = tid + CTPB * i;  // first 4096 real samples only
        float2 y = s[stid ^ swz(CTPB * i)];
        yo[t] = make_float2(y.x * sc, y.y * sc);
    }
}

// ---------- transpose out + skip: out[b,t,h] = yt[(b*512+h),t] + D[h]*x[b,t,h], float4 ----------
__global__ __launch_bounds__(TPB) void transpose_out(const float* __restrict__ yt,
                                                     const float* __restrict__ x,
                                                     const float* __restrict__ Dv,
                                                     float* __restrict__ out) {
    __shared__ float tile[64][65];
    const int b = blockIdx.z, t0 = blockIdx.y * 64, h0 = blockIdx.x * 64;
    const int tid = threadIdx.x;
    const float* yp = yt + ((size_t)(b * 512 + h0)) * 4096 + t0;
#pragma unroll
    for (int i = 0; i < 4; ++i) {
        int idx = tid + TPB * i;
        int hl = idx >> 4, tq = idx & 15;
        float4 v = ((const float4*)(yp + (size_t)hl * 4096))[tq];
        tile[tq * 4 + 0][hl] = v.x; tile[tq * 4 + 1][hl] = v.y;
        tile[tq * 4 + 2][hl] = v.z; tile[tq * 4 + 3][hl] = v.w;
    }
    __syncthreads();
    const float4* xv = (const float4*)(x + ((size_t)b * 4096 + t0) * 512 + h0);
    float4* ov = (float4*)(out + ((size_t)b * 4096 + t0) * 512 + h0);
    const float4* D4 = (const float4*)(Dv + h0);
#pragma unroll
    for (int i = 0; i < 4; ++i) {
        int idx = tid + TPB * i;
        int tl = idx >> 4, hq = idx & 15;
        float4 xvv = xv[(size_t)tl * 128 + hq];
        float4 d = D4[hq];
        float4 v = make_float4(tile[tl][4 * hq + 0] + d.x * xvv.x,
                               tile[tl][4 * hq + 1] + d.y * xvv.y,
                               tile[tl][4 * hq + 2] + d.z * xvv.z,
                               tile[tl][4 * hq + 3] + d.w * xvv.w);
        ov[(size_t)tl * 128 + hq] = v;
    }
}

extern "C" void kernel_launch(void* const* d_in, const int* in_sizes, int n_in,
                              void* d_out, int out_size, void* d_ws, size_t ws_size,
                              hipStream_t stream) {
    (void)in_sizes; (void)n_in; (void)out_size; (void)ws_size;
    const float* x      = (const float*)d_in[0];  // [8,4096,512]
    const float* log_dt = (const float*)d_in[1];  // [512]
    const float* w_ri   = (const float*)d_in[2];  // [32,2]
    const float* Bri    = (const float*)d_in[3];  // [512,2,32,2]
    const float* Cri    = (const float*)d_in[4];  // [512,2,32,2]
    const float* Dv     = (const float*)d_in[5];  // [512]
    float* out = (float*)d_out;

    char* ws = (char*)d_ws;
    float*  xt = (float*)(ws);                  // 8*512*4096*4 = 67,108,864 B (reused as yt)
    float2* kf = (float2*)(ws + 67108864);      // 512*2049*8   =  8,392,704 B
    float2* Kt = (float2*)(ws + 75501568);      // 512*4097*8   = 16,781,312 B  (end ~92.3 MB)

    kf_kernel<<<dim3(512, 4), TPB, 0, stream>>>(log_dt, w_ri, Bri, Cri, kf);
    kprep_kernel<<<512, TPB, 0, stream>>>(kf, Kt);
    transpose_in<<<dim3(8, 64, 8), TPB, 0, stream>>>(x, xt);
    conv_kernel<<<4096, CTPB, 0, stream>>>(xt, Kt, xt);  // y overwrites xt rows
    transpose_out<<<dim3(8, 64, 8), TPB, 0, stream>>>(xt, x, Dv, out);
}

// Round 4
// 282.596 us; speedup vs baseline: 1.4642x; 1.0725x over previous
//
#include <hip/hip_runtime.h>
#include <math.h>

#define TPB 256
#define CTPB 512
#define KTPB 512

// ---------- complex helpers ----------
__device__ __forceinline__ float2 cmul(float2 a, float2 b) {
    return make_float2(a.x * b.x - a.y * b.y, a.x * b.y + a.y * b.x);
}
__device__ __forceinline__ float2 cdivf(float2 a, float2 b) {
    float inv = 1.0f / (b.x * b.x + b.y * b.y);
    return make_float2((a.x * b.x + a.y * b.y) * inv, (a.y * b.x - a.x * b.y) * inv);
}
__device__ __forceinline__ float2 cadd(float2 a, float2 b) { return make_float2(a.x + b.x, a.y + b.y); }
__device__ __forceinline__ float2 csub(float2 a, float2 b) { return make_float2(a.x - b.x, a.y - b.y); }
__device__ __forceinline__ float2 mul_i(float2 a, float d) {  // a * (i*d)
    return make_float2(-d * a.y, d * a.x);
}
__device__ __forceinline__ int brev11(int x) { return (int)(__brev((unsigned)x) >> 21); }
// base-8 digit reversal of a 12-bit index (4 digits)
__device__ __forceinline__ int rev8(int x) {
    return ((x & 7) << 9) | (((x >> 3) & 7) << 6) | (((x >> 6) & 7) << 3) | ((x >> 9) & 7);
}
// LDS bank swizzle. GF(2)-LINEAR: swz(a^b) == swz(a)^swz(b) -> per-tap offsets fold
// to compile-time XOR constants.
__device__ __forceinline__ int swz(int i) { return i ^ ((i >> 4) & 15) ^ ((i >> 8) & 15); }

// ---------- 8-point DFT cores ----------
__device__ __forceinline__ void dft8(const float2* x, float2* y, float d) {
    const float r = 0.70710678118f;
    float2 s0 = cadd(x[0], x[4]), t0 = csub(x[0], x[4]);
    float2 s1 = cadd(x[1], x[5]), t1 = csub(x[1], x[5]);
    float2 s2 = cadd(x[2], x[6]), t2 = csub(x[2], x[6]);
    float2 s3 = cadd(x[3], x[7]), t3 = csub(x[3], x[7]);
    t1 = cmul(t1, make_float2(r, d * r));
    t2 = mul_i(t2, d);
    t3 = cmul(t3, make_float2(-r, d * r));
    float2 u0 = cadd(s0, s2), v0 = csub(s0, s2);
    float2 u1 = cadd(s1, s3), v1 = mul_i(csub(s1, s3), d);
    y[0] = cadd(u0, u1); y[4] = csub(u0, u1);
    y[2] = cadd(v0, v1); y[6] = csub(v0, v1);
    float2 p0 = cadd(t0, t2), q0 = csub(t0, t2);
    float2 p1 = cadd(t1, t3), q1 = mul_i(csub(t1, t3), d);
    y[1] = cadd(p0, p1); y[5] = csub(p0, p1);
    y[3] = cadd(q0, q1); y[7] = csub(q0, q1);
}

// dft8 with x[4..7] == 0 (zero-padded upper half): level 1 vanishes (s_i = t_i = x_i)
__device__ __forceinline__ void dft8z(float2 x0, float2 x1, float2 x2, float2 x3,
                                      float2* y, float d) {
    const float r = 0.70710678118f;
    float2 u0 = cadd(x0, x2), v0 = csub(x0, x2);
    float2 u1 = cadd(x1, x3), v1 = mul_i(csub(x1, x3), d);
    float2 t1 = cmul(x1, make_float2(r, d * r));
    float2 t2 = mul_i(x2, d);
    float2 t3 = cmul(x3, make_float2(-r, d * r));
    float2 p0 = cadd(x0, t2), q0 = csub(x0, t2);
    float2 p1 = cadd(t1, t3), q1 = mul_i(csub(t1, t3), d);
    y[0] = cadd(u0, u1); y[4] = csub(u0, u1);
    y[2] = cadd(v0, v1); y[6] = csub(v0, v1);
    y[1] = cadd(p0, p1); y[5] = csub(p0, p1);
    y[3] = cadd(q0, q1); y[7] = csub(q0, q1);
}

// dft8 computing only outputs y[0..3] (the '+' halves) — for the discarded tail
__device__ __forceinline__ void dft8_lo(const float2* x, float2* y, float d) {
    const float r = 0.70710678118f;
    float2 s0 = cadd(x[0], x[4]), t0 = csub(x[0], x[4]);
    float2 s1 = cadd(x[1], x[5]), t1 = csub(x[1], x[5]);
    float2 s2 = cadd(x[2], x[6]), t2 = csub(x[2], x[6]);
    float2 s3 = cadd(x[3], x[7]), t3 = csub(x[3], x[7]);
    t1 = cmul(t1, make_float2(r, d * r));
    t2 = mul_i(t2, d);
    t3 = cmul(t3, make_float2(-r, d * r));
    float2 u0 = cadd(s0, s2), v0 = csub(s0, s2);
    float2 u1 = cadd(s1, s3), v1 = mul_i(csub(s1, s3), d);
    y[0] = cadd(u0, u1);
    y[2] = cadd(v0, v1);
    float2 p0 = cadd(t0, t2), q0 = csub(t0, t2);
    float2 p1 = cadd(t1, t3), q1 = mul_i(csub(t1, t3), d);
    y[1] = cadd(p0, p1);
    y[3] = cadd(q0, q1);
}

// ---------- single radix-8 stages for conv (1 butterfly/thread, N=4096, NT=512) ----------
template <int HB, int DIR>
__device__ __forceinline__ void dif_stage(float2* s, int tid) {
    __syncthreads();
    const int h = 1 << HB;
    int j = tid & (h - 1);
    int base = ((tid >> HB) << (HB + 3)) + j;
    int s0 = swz(base);
    float2 x[8];
#pragma unroll
    for (int k = 0; k < 8; ++k) x[k] = s[s0 ^ swz(k << HB)];
    float2 y[8];
    dft8(x, y, (float)DIR);
    if constexpr (HB != 0) {
        float ang = (float)DIR * 6.283185307179586f / (float)(h << 3) * (float)j;
        float c, sn;
        __sincosf(ang, &sn, &c);
        float2 w = make_float2(c, sn), wm = w;
        s[s0] = y[0];
#pragma unroll
        for (int m = 1; m < 8; ++m) {
            s[s0 ^ swz(m << HB)] = cmul(wm, y[m]);
            wm = cmul(wm, w);
        }
    } else {  // j == 0 -> w == 1: no twiddles
#pragma unroll
        for (int m = 0; m < 8; ++m) s[s0 ^ swz(m << HB)] = y[m];
    }
}

template <int HB, int DIR>
__device__ __forceinline__ void dit_stage(float2* s, int tid) {
    __syncthreads();
    const int h = 1 << HB;
    int j = tid & (h - 1);
    int base = ((tid >> HB) << (HB + 3)) + j;
    int s0 = swz(base);
    float2 x[8];
    if constexpr (HB != 0) {
        float ang = (float)DIR * 6.283185307179586f / (float)(h << 3) * (float)j;
        float c, sn;
        __sincosf(ang, &sn, &c);
        float2 w = make_float2(c, sn);
        x[0] = s[s0];
        float2 wm = w;
#pragma unroll
        for (int k = 1; k < 8; ++k) {
            x[k] = cmul(wm, s[s0 ^ swz(k << HB)]);
            wm = cmul(wm, w);
        }
    } else {  // j == 0 -> no twiddles
#pragma unroll
        for (int k = 0; k < 8; ++k) x[k] = s[s0 ^ swz(k << HB)];
    }
    float2 y[8];
    dft8(x, y, (float)DIR);
#pragma unroll
    for (int m = 0; m < 8; ++m) s[s0 ^ swz(m << HB)] = y[m];
}

// ---------- generic radix-8 DIF (for kprep), with h=1 twiddle skip ----------
template <int LOGN, int NT>
__device__ void fft8_dif(float2* s, int tid, float dir) {
    const int N = 1 << LOGN;
#pragma unroll
    for (int hb = LOGN - 3; hb >= 0; hb -= 3) {
        const int h = 1 << hb;
        const float astep = dir * 6.283185307179586f / (float)(h << 3);
        __syncthreads();
#pragma unroll
        for (int it = 0; it < (N >> 3) / NT; ++it) {
            const int b = tid + it * NT;
            int j = b & (h - 1);
            int base = ((b >> hb) << (hb + 3)) + j;
            int s0 = swz(base);
            float2 x[8];
#pragma unroll
            for (int k = 0; k < 8; ++k) x[k] = s[s0 ^ swz(k << hb)];
            float2 y[8];
            dft8(x, y, dir);
            if (hb != 0) {  // folds: hb is unroll-constant
                float ang = astep * (float)j;
                float c, sn;
                __sincosf(ang, &sn, &c);
                float2 w = make_float2(c, sn), wm = w;
                s[s0] = y[0];
#pragma unroll
                for (int m = 1; m < 8; ++m) {
                    s[s0 ^ swz(m << hb)] = cmul(wm, y[m]);
                    wm = cmul(wm, w);
                }
            } else {
#pragma unroll
                for (int m = 0; m < 8; ++m) s[s0 ^ swz(m << hb)] = y[m];
            }
        }
    }
    __syncthreads();
}

// ---------- radix-2 DIF (unswizzled), for the 2048-pt kernel inverse only ----------
template <int LOGN, int NT>
__device__ void fft_dif2(float2* s, int tid, float dir) {
    const int N = 1 << LOGN;
    for (int st = LOGN - 1; st >= 0; --st) {
        __syncthreads();
        int half = 1 << st;
        for (int b = tid; b < (N >> 1); b += NT) {
            int j  = b & (half - 1);
            int i0 = ((b >> st) << (st + 1)) + j;
            int i1 = i0 + half;
            float2 u = s[i0], v = s[i1];
            float2 d = make_float2(u.x - v.x, u.y - v.y);
            s[i0] = make_float2(u.x + v.x, u.y + v.y);
            if (half > 1) {
                float ang = dir * 3.14159265358979f * (float)j / (float)half;
                float c, sn;
                __sincosf(ang, &sn, &c);
                s[i1] = cmul(make_float2(c, sn), d);
            } else {
                s[i1] = d;
            }
        }
    }
    __syncthreads();
}

// ---------- kernel A: k_f[h, f] via Cauchy + Woodbury, collapsed pair algebra ----------
__global__ __launch_bounds__(TPB) void kf_kernel(
    const float* __restrict__ log_dt, const float* __restrict__ w_ri,
    const float* __restrict__ Bri, const float* __restrict__ Cri,
    float2* __restrict__ kf) {
    __shared__ float2 wds[32];
    __shared__ float aab[4][32], rab[4][32];
    __shared__ float qn[32], pn[32];
    const int h   = blockIdx.x;
    const int tid = threadIdx.x;
    const float dt = expf(log_dt[h]);
    if (tid < 32) {
        float wr = w_ri[2 * tid] * dt, wi = w_ri[2 * tid + 1] * dt;
        wds[tid] = make_float2(wr, wi);
        qn[tid]  = wr * wr + wi * wi;
        pn[tid]  = -2.0f * wr;
    }
    __syncthreads();
    if (tid < 128) {
        int a = tid >> 6, b = (tid >> 5) & 1, n = tid & 31;
        const float* Cp = Cri + (((h * 2 + a) * 32) + n) * 2;
        const float* Bp = Bri + (((h * 2 + b) * 32) + n) * 2;
        float Cr = Cp[0], Ci = Cp[1], Br = Bp[0], Bi = Bp[1];
        float2 v = make_float2(Cr * Br + Ci * Bi, Cr * Bi - Ci * Br);  // conj(C)*B
        float2 wd = wds[n];
        aab[a * 2 + b][n] = -2.0f * (v.x * wd.x + v.y * wd.y);
        rab[a * 2 + b][n] = 2.0f * v.x;
    }
    __syncthreads();
    const int by   = blockIdx.y;
    const int fend = (by == 3) ? 2049 : (by + 1) * 512;
    for (int f = by * 512 + tid; f < fend; f += TPB) {
        float th = (6.283185307179586f / 4096.0f) * (float)f;
        float cf = cosf(th), sf = sinf(th);
        float2 den = make_float2(1.0f + cf, -sf);      // 1 + freq
        float zt  = 2.0f * tanf(0.5f * th);
        float zt2 = zt * zt;
        float2 r00 = make_float2(0.f, 0.f), r01 = r00, r10 = r00, r11 = r00;
        for (int n = 0; n < 32; ++n) {
            float c   = qn[n] - zt2;
            float d   = pn[n] * zt;
            float inv = 1.0f / (c * c + d * d);
            float cc = c * inv, dd = d * inv;
            float a0 = aab[0][n], b0 = rab[0][n] * zt;
            r00.x += a0 * cc + b0 * dd; r00.y += b0 * cc - a0 * dd;
            float a1 = aab[1][n], b1 = rab[1][n] * zt;
            r01.x += a1 * cc + b1 * dd; r01.y += b1 * cc - a1 * dd;
            float a2 = aab[2][n], b2 = rab[2][n] * zt;
            r10.x += a2 * cc + b2 * dd; r10.y += b2 * cc - a2 * dd;
            float a3 = aab[3][n], b3 = rab[3][n] * zt;
            r11.x += a3 * cc + b3 * dd; r11.y += b3 * cc - a3 * dd;
        }
        r00.x *= dt; r00.y *= dt; r01.x *= dt; r01.y *= dt;
        r10.x *= dt; r10.y *= dt; r11.x *= dt; r11.y *= dt;
        float2 q  = cdivf(cmul(r01, r10), make_float2(1.0f + r11.x, r11.y));
        float2 k0 = make_float2(r00.x - q.x, r00.y - q.y);
        float2 kv = cmul(k0, cdivf(make_float2(2.0f, 0.0f), den));
        kf[h * 2049 + f] = kv;
    }
}

// ---------- kernel B (fused): irfft_4096(k_f) -> zero-pad -> rfft_8192, store digit-rev ----------
__global__ __launch_bounds__(KTPB) void kprep_kernel(const float2* __restrict__ kf,
                                                     float2* __restrict__ Kt) {
    __shared__ float2 s[4096];
    const int hh = blockIdx.x, tid = threadIdx.x;
    const float2* X = kf + hh * 2049;
    for (int m = tid; m < 2048; m += KTPB) {
        float2 Xm = X[m];
        float2 Xc = X[2048 - m];
        if (m == 0) { Xm.y = 0.0f; Xc.y = 0.0f; }
        float2 A  = make_float2(Xm.x + Xc.x, Xm.y - Xc.y);
        float2 Bv = make_float2(Xm.x - Xc.x, Xm.y + Xc.y);
        float ang = (3.14159265358979f / 2048.0f) * (float)m;
        float c, sn;
        __sincosf(ang, &sn, &c);
        float2 O = cmul(make_float2(c, sn), Bv);
        s[m] = make_float2(0.5f * (A.x - O.y), 0.5f * (A.y + O.x));
    }
    fft_dif2<11, KTPB>(s, tid, +1.0f);  // inverse, natural-in -> bitrev-out (unswizzled)
    float2 reg[4];
    const float sc = 1.0f / 2048.0f;
#pragma unroll
    for (int i = 0; i < 4; ++i) {
        int t = tid + KTPB * i;  // 0..2047
        float2 v = s[brev11(t)];
        reg[i] = make_float2(v.x * sc, v.y * sc);
    }
    __syncthreads();
#pragma unroll
    for (int i = 0; i < 4; ++i) {
        int t = tid + KTPB * i;
        s[swz(t)]        = reg[i];
        s[swz(t + 2048)] = make_float2(0.f, 0.f);
    }
    fft8_dif<12, KTPB>(s, tid, -1.0f);  // slot p holds Y[rev8(p)]
    float2* K = Kt + (size_t)hh * 4097;
    for (int p = tid; p < 4096; p += KTPB) {
        int j  = rev8(p);
        int jc = (4096 - j) & 4095;
        int pc = rev8(jc);
        float2 Yj = s[swz(p)], Yc = s[swz(pc)];
        float2 A  = make_float2(Yj.x + Yc.x, Yj.y - Yc.y);
        float2 Bv = make_float2(Yj.x - Yc.x, Yj.y + Yc.y);
        float ang = -(3.14159265358979f / 4096.0f) * (float)j;
        float c, sn;
        __sincosf(ang, &sn, &c);
        float2 t2 = cmul(make_float2(c, sn), make_float2(Bv.y, -Bv.x));
        K[p] = make_float2(0.5f * (A.x + t2.x), 0.5f * (A.y + t2.y));
        if (p == 0) K[4096] = make_float2(Yj.x - Yj.y, 0.0f);
    }
}

// ---------- transpose in: x[b,t,h] -> xt[(b*512+h), t], float4 both sides ----------
__global__ __launch_bounds__(TPB) void transpose_in(const float* __restrict__ x,
                                                    float* __restrict__ xt) {
    __shared__ float tile[64][65];
    const int b = blockIdx.z, t0 = blockIdx.y * 64, h0 = blockIdx.x * 64;
    const int tid = threadIdx.x;
    const float4* xv = (const float4*)(x + ((size_t)b * 4096 + t0) * 512 + h0);
#pragma unroll
    for (int i = 0; i < 4; ++i) {
        int idx = tid + TPB * i;       // 0..1023
        int tl = idx >> 4, hq = idx & 15;
        float4 v = xv[(size_t)tl * 128 + hq];
        tile[tl][hq * 4 + 0] = v.x; tile[tl][hq * 4 + 1] = v.y;
        tile[tl][hq * 4 + 2] = v.z; tile[tl][hq * 4 + 3] = v.w;
    }
    __syncthreads();
    float* xo = xt + ((size_t)(b * 512 + h0)) * 4096 + t0;
#pragma unroll
    for (int i = 0; i < 4; ++i) {
        int idx = tid + TPB * i;
        int hl = idx >> 4, tq = idx & 15;
        float4 v = make_float4(tile[tq * 4 + 0][hl], tile[tq * 4 + 1][hl],
                               tile[tq * 4 + 2][hl], tile[tq * 4 + 3][hl]);
        ((float4*)(xo + (size_t)hl * 4096))[tq] = v;
    }
}

// ---------- fused conv: y = irfft8192(rfft8192(x)*K~)[0:4096]*1 + D*x, radix-8, reg end-stages ----------
__global__ __launch_bounds__(CTPB) void conv_kernel(const float* xt,
                                                    const float2* __restrict__ Kt,
                                                    const float* __restrict__ Dv,
                                                    float* yt) {
    __shared__ float2 s[4096];
    const int row = blockIdx.x, tid = threadIdx.x;
    const int hch = row & 511;
    const int stid = swz(tid);
    const float2* xr = (const float2*)(xt + (size_t)row * 4096);

    // ---- D1 (DIF h=512) in registers; upper half is the zero pad -> dft8z
    {
        float2 x0 = xr[tid], x1 = xr[tid + 512], x2 = xr[tid + 1024], x3 = xr[tid + 1536];
        float2 y[8];
        dft8z(x0, x1, x2, x3, y, -1.0f);
        float ang = -(6.283185307179586f / 4096.0f) * (float)tid;
        float c, sn;
        __sincosf(ang, &sn, &c);
        float2 w = make_float2(c, sn), wm = w;
        s[stid] = y[0];
#pragma unroll
        for (int m = 1; m < 8; ++m) {
            s[stid ^ swz(m << 9)] = cmul(wm, y[m]);
            wm = cmul(wm, w);
        }
    }
    dif_stage<6, -1>(s, tid);
    dif_stage<3, -1>(s, tid);
    dif_stage<0, -1>(s, tid);
    __syncthreads();
    // ---- pointwise multiply in digit-reversed Hermitian-packed domain
    const float2* K = Kt + (size_t)hch * 4097;
#pragma unroll
    for (int i = 0; i < 8; ++i) {
        int p  = tid + CTPB * i;
        int sp = stid ^ swz(CTPB * i);
        if (p == 0) {  // j=0 pairs with bin 4096
            float2 Y0 = s[sp];
            float X0 = Y0.x + Y0.y;
            float Xn = Y0.x - Y0.y;
            float Z0 = X0 * K[0].x;
            float Zn = Xn * K[4096].x;
            s[sp] = make_float2(0.5f * (Z0 + Zn), 0.5f * (Z0 - Zn));
            continue;
        }
        int j  = rev8(p);
        int jc = 4096 - j;
        int pc = rev8(jc & 4095);
        if (pc < p) continue;  // pair owner has the smaller slot
        float2 Yj = s[sp], Yc = s[swz(pc)];
        float2 A  = make_float2(Yj.x + Yc.x, Yj.y - Yc.y);
        float2 Bv = make_float2(Yj.x - Yc.x, Yj.y + Yc.y);
        float ang = -(3.14159265358979f / 4096.0f) * (float)j;
        float c, sn;
        __sincosf(ang, &sn, &c);
        float2 W = make_float2(c, sn);
        float2 t2 = cmul(W, make_float2(Bv.y, -Bv.x));
        float2 Xj = make_float2(0.5f * (A.x + t2.x), 0.5f * (A.y + t2.y));
        float2 t2c = cmul(make_float2(-W.x, W.y), make_float2(Bv.y, Bv.x));
        float2 Xc2 = make_float2(0.5f * (A.x + t2c.x), 0.5f * (-A.y + t2c.y));
        float2 Zj = cmul(Xj, K[p]);
        float2 Zc = cmul(Xc2, K[pc]);
        float2 A2 = make_float2(Zj.x + Zc.x, Zj.y - Zc.y);
        float2 B2 = make_float2(Zj.x - Zc.x, Zj.y + Zc.y);
        float2 O2 = cmul(make_float2(W.x, -W.y), B2);
        s[sp] = make_float2(0.5f * (A2.x - O2.y), 0.5f * (A2.y + O2.x));
        if (pc != p) {
            float2 O2c = cmul(make_float2(-W.x, -W.y), make_float2(-B2.x, B2.y));
            s[swz(pc)] = make_float2(0.5f * (A2.x - O2c.y), 0.5f * (-A2.y + O2c.x));
        }
    }
    dit_stage<0, 1>(s, tid);
    dit_stage<3, 1>(s, tid);
    dit_stage<6, 1>(s, tid);
    __syncthreads();
    // ---- I4 (DIT h=512) in registers; keep only first 4096 samples; fuse D*x skip
    {
        float ang = (6.283185307179586f / 4096.0f) * (float)tid;
        float c, sn;
        __sincosf(ang, &sn, &c);
        float2 w = make_float2(c, sn);
        float2 x[8];
        x[0] = s[stid];
        float2 wm = w;
#pragma unroll
        for (int k = 1; k < 8; ++k) {
            x[k] = cmul(wm, s[stid ^ swz(k << 9)]);
            wm = cmul(wm, w);
        }
        float2 y[4];
        dft8_lo(x, y, 1.0f);
        const float D = Dv[hch];
        float2* yo = (float2*)(yt + (size_t)row * 4096);
        const float sc = 1.0f / 4096.0f;
#pragma unroll
        for (int m = 0; m < 4; ++m) {
            int t2 = tid + (m << 9);
            float2 xin = xr[t2];  // re-read own row (L2-warm); xt/yt alias is per-element safe
            yo[t2] = make_float2(y[m].x * sc + D * xin.x, y[m].y * sc + D * xin.y);
        }
    }
}

// ---------- transpose out (pure): out[b,t,h] = yt[(b*512+h),t] ----------
__global__ __launch_bounds__(TPB) void transpose_out(const float* __restrict__ yt,
                                                     float* __restrict__ out) {
    __shared__ float tile[64][65];
    const int b = blockIdx.z, t0 = blockIdx.y * 64, h0 = blockIdx.x * 64;
    const int tid = threadIdx.x;
    const float* yp = yt + ((size_t)(b * 512 + h0)) * 4096 + t0;
#pragma unroll
    for (int i = 0; i < 4; ++i) {
        int idx = tid + TPB * i;
        int hl = idx >> 4, tq = idx & 15;
        float4 v = ((const float4*)(yp + (size_t)hl * 4096))[tq];
        tile[tq * 4 + 0][hl] = v.x; tile[tq * 4 + 1][hl] = v.y;
        tile[tq * 4 + 2][hl] = v.z; tile[tq * 4 + 3][hl] = v.w;
    }
    __syncthreads();
    float4* ov = (float4*)(out + ((size_t)b * 4096 + t0) * 512 + h0);
#pragma unroll
    for (int i = 0; i < 4; ++i) {
        int idx = tid + TPB * i;
        int tl = idx >> 4, hq = idx & 15;
        float4 v = make_float4(tile[tl][4 * hq + 0], tile[tl][4 * hq + 1],
                               tile[tl][4 * hq + 2], tile[tl][4 * hq + 3]);
        ov[(size_t)tl * 128 + hq] = v;
    }
}

extern "C" void kernel_launch(void* const* d_in, const int* in_sizes, int n_in,
                              void* d_out, int out_size, void* d_ws, size_t ws_size,
                              hipStream_t stream) {
    (void)in_sizes; (void)n_in; (void)out_size; (void)ws_size;
    const float* x      = (const float*)d_in[0];  // [8,4096,512]
    const float* log_dt = (const float*)d_in[1];  // [512]
    const float* w_ri   = (const float*)d_in[2];  // [32,2]
    const float* Bri    = (const float*)d_in[3];  // [512,2,32,2]
    const float* Cri    = (const float*)d_in[4];  // [512,2,32,2]
    const float* Dv     = (const float*)d_in[5];  // [512]
    float* out = (float*)d_out;

    char* ws = (char*)d_ws;
    float*  xt = (float*)(ws);                  // 8*512*4096*4 = 67,108,864 B (reused as yt)
    float2* kf = (float2*)(ws + 67108864);      // 512*2049*8   =  8,392,704 B
    float2* Kt = (float2*)(ws + 75501568);      // 512*4097*8   = 16,781,312 B  (end ~92.3 MB)

    kf_kernel<<<dim3(512, 4), TPB, 0, stream>>>(log_dt, w_ri, Bri, Cri, kf);
    kprep_kernel<<<512, KTPB, 0, stream>>>(kf, Kt);
    transpose_in<<<dim3(8, 64, 8), TPB, 0, stream>>>(x, xt);
    conv_kernel<<<4096, CTPB, 0, stream>>>(xt, Kt, Dv, xt);  // y(+skip) overwrites xt rows
    transpose_out<<<dim3(8, 64, 8), TPB, 0, stream>>>(xt, out);
}